// Round 8
// baseline (290.895 us; speedup 1.0000x reference)
//
#include <hip/hip_runtime.h>
#include <cmath>

#define BB 8
#define CC 64
#define HH 128
#define WW 128

typedef short s8v __attribute__((ext_vector_type(8)));      // raw 16B move
typedef float f4v __attribute__((ext_vector_type(4)));      // 4 fp32 acc
typedef _Float16 h8 __attribute__((ext_vector_type(8)));    // 8 f16 (4 VGPRs)
typedef unsigned short u16;
typedef u16 u4v __attribute__((ext_vector_type(4)));

__device__ __forceinline__ u16 f2h(float f) {
    _Float16 h = (_Float16)f;
    return __builtin_bit_cast(u16, h);
}
__device__ __forceinline__ _Float16 h_from_bits(u16 b) {
    return __builtin_bit_cast(_Float16, b);
}

// ---------------------------------------------------------------------------
// Fused weight transforms (fp32 -> f16).
//  W1  [oc64][ic128][3][3] -> W1t  [tap9][oc64][ic128]
//  Woff[18]/Wmod[9]        -> Womt [tap9][o32(27)][c64]
//  Wdcn[oc][c][k]          -> Wdt  [k9][oc64][c64]
// ---------------------------------------------------------------------------
__global__ void wfuse_kernel(const float* __restrict__ W1, const float* __restrict__ Woff,
                             const float* __restrict__ Wmod, const float* __restrict__ Wdcn,
                             u16* __restrict__ W1t, u16* __restrict__ Womt,
                             u16* __restrict__ Wdt)
{
    int idx = blockIdx.x * 256 + threadIdx.x;
    if (idx < 73728) {
        const int ic = idx & 127;
        const int oc = (idx >> 7) & 63;
        const int t  = idx >> 13;
        W1t[idx] = f2h(W1[((size_t)(oc * 128 + ic)) * 9 + t]);
        return;
    }
    idx -= 73728;
    if (idx < 18432) {
        const int c = idx & 63;
        const int o = (idx >> 6) & 31;
        const int t = idx >> 11;
        float v = 0.f;
        if (o < 18)      v = Woff[((size_t)(o * 64 + c)) * 9 + t];
        else if (o < 27) v = Wmod[((size_t)((o - 18) * 64 + c)) * 9 + t];
        Womt[idx] = f2h(v);
        return;
    }
    idx -= 18432;
    if (idx < 36864) {
        const int c  = idx & 63;
        const int oc = (idx >> 6) & 63;
        const int k  = idx >> 12;
        Wdt[idx] = f2h(Wdcn[((size_t)(oc * 64 + c)) * 9 + k]);
    }
}

// ---------------------------------------------------------------------------
// Kernel A: conv1 implicit-GEMM f16 MFMA. 16x16 px x 64 oc per block.
// Stages DIRECTLY from NCHW fp32 (inline f16 convert, scalar LDS writes) —
// the former x2nhwc relayout kernel is gone. Weights staged in LDS (r6
// lesson: global loads inside the MFMA loop poison the vmcnt chain).
// feat out: f16 NHWC [B][H][W][64].
// ---------------------------------------------------------------------------
__global__ __launch_bounds__(256)
void conv1_mfma_kernel(const float* __restrict__ xvq, const float* __restrict__ xres,
                       const u16* __restrict__ W1t, const float* __restrict__ b1,
                       u16* __restrict__ feath)
{
    __shared__ u16 sTile[324 * 36];   // [18x18][ic32 pad36] 23.3 KB
    __shared__ u16 sW[576 * 36];      // [tap*64+oc][ic32 pad36] 41.5 KB

    const int x0 = blockIdx.x * 16;
    const int y0 = blockIdx.y * 16;
    const int b  = blockIdx.z;
    const int tid = threadIdx.x;
    const int lane = tid & 63;
    const int wave = tid >> 6;
    const int lm = lane & 15;
    const int kg = lane >> 4;

    f4v acc[4][4];
#pragma unroll
    for (int i = 0; i < 4; ++i)
#pragma unroll
        for (int j = 0; j < 4; ++j) acc[i][j] = (f4v)0.f;

    for (int chunk = 0; chunk < 4; ++chunk) {
        const int c0 = chunk * 32;
        __syncthreads();
        // stage A-tile from NCHW fp32: 324 px x 32 ic scalar converts
        for (int i = 0; i < 41; ++i) {
            const int idx = tid + 256 * i;
            if (idx < 10368) {
                const int icp = idx / 324;          // 0..31
                const int pix = idx - icp * 324;
                const int gic = c0 + icp;
                const float* src = (gic < 64)
                    ? xvq  + ((size_t)(b * 64 + gic)) * HH * WW
                    : xres + ((size_t)(b * 64 + (gic - 64))) * HH * WW;
                const int gy = y0 - 1 + pix / 18;
                const int gx = x0 - 1 + pix % 18;
                float v = 0.f;
                if ((unsigned)gy < HH && (unsigned)gx < WW)
                    v = src[gy * WW + gx];
                sTile[pix * 36 + icp] = f2h(v);
            }
        }
        // stage weights: 576 rows x 32ch = 2304 x 16B
        for (int i = 0; i < 9; ++i) {
            const int idx = tid + 256 * i;
            const int row = idx >> 2;      // t*64 + oc
            const int q   = idx & 3;
            *(s8v*)&sW[row * 36 + q * 8] =
                *(const s8v*)(W1t + (size_t)row * 128 + c0 + q * 8);
        }
        __syncthreads();

#pragma unroll
        for (int t = 0; t < 9; ++t) {
            const int dy = t / 3, dx = t % 3;
            h8 a[4], bq[4];
#pragma unroll
            for (int mt = 0; mt < 4; ++mt) {
                const int p = wave * 64 + mt * 16 + lm;
                const int sidx = ((p >> 4) + dy) * 18 + (p & 15) + dx;
                a[mt] = *(const h8*)&sTile[sidx * 36 + kg * 8];
            }
#pragma unroll
            for (int nt = 0; nt < 4; ++nt) {
                const int oc = nt * 16 + lm;
                bq[nt] = *(const h8*)&sW[(t * 64 + oc) * 36 + kg * 8];
            }
#pragma unroll
            for (int mt = 0; mt < 4; ++mt)
#pragma unroll
                for (int nt = 0; nt < 4; ++nt)
                    acc[mt][nt] = __builtin_amdgcn_mfma_f32_16x16x32_f16(
                        a[mt], bq[nt], acc[mt][nt], 0, 0, 0);
        }
    }

#pragma unroll
    for (int nt = 0; nt < 4; ++nt) {
        const int oc = nt * 16 + lm;
        const float bias = b1[oc];
#pragma unroll
        for (int mt = 0; mt < 4; ++mt)
#pragma unroll
            for (int r = 0; r < 4; ++r) {
                const int p = wave * 64 + mt * 16 + kg * 4 + r;
                const int y = y0 + (p >> 4), x = x0 + (p & 15);
                feath[(((size_t)b * HH + y) * WW + x) * CC + oc] =
                    f2h(acc[mt][nt][r] + bias);
            }
    }
}

// ---------------------------------------------------------------------------
// Kernel C: FUSED offset/mod conv + deformable sampling + einsum.
// Phase 1: stage 10x10x64 feat tile (aliased into sV buffer), MFMA om
//          (M=64px, N=32(27), K=576; Womt B-frags from global), sigmoid->sOm.
// Phase 2: bilinear records into LDS (r5 form).
// Phase 3: r5 gather loop verbatim: sV dbuf, 1-tap prefetch, global Wd B-frags.
// LDS total 39.4 KB (same as r5's dcn).
// ---------------------------------------------------------------------------
__global__ __launch_bounds__(256)
void dcn_mfma_kernel(const u16* __restrict__ feath, const u16* __restrict__ Womt,
                     const u16* __restrict__ Wdt,
                     const float* __restrict__ boff, const float* __restrict__ bmod,
                     const float* __restrict__ bdcn, float* __restrict__ out)
{
    __shared__ u16 sV[2 * 4608];      // dbuf [p][c64 pad72]; also aliases sFeat
    __shared__ float sOm[64 * 28];    // [p][27 pad28] 7.2 KB
    __shared__ int sOffs[576 * 4];    // [k*64+p][corner] 9.2 KB
    __shared__ u16 sWts[576 * 4];     // [k*64+p][corner] f16 w*mod 4.6 KB

    const int b  = blockIdx.z;
    const int x0 = blockIdx.x * 8;
    const int y0 = blockIdx.y * 8;
    const int tid = threadIdx.x;
    const int lane = tid & 63;
    const int wave = tid >> 6;
    const int wi = wave >> 1;
    const int wj = wave & 1;
    const int lm = lane & 15;
    const int kg = lane >> 4;

    const u16* fb = feath + ((size_t)b * HH * WW) * CC;

    // ---- phase 1a: stage 10x10 feat tile [pix][c64 pad72] into sV alias ----
    u16* sFeat = sV;                  // 100*72 = 7200 u16, dead before gather
    for (int i = 0; i < 4; ++i) {
        const int idx = tid + 256 * i;              // 800 ushort8
        if (idx < 800) {
            const int pix = idx >> 3;
            const int q   = idx & 7;
            const int gy = y0 - 1 + pix / 10;
            const int gx = x0 - 1 + pix % 10;
            s8v v = (s8v)0;
            if ((unsigned)gy < HH && (unsigned)gx < WW)
                v = *(const s8v*)(fb + ((size_t)(gy * WW + gx)) * CC + q * 8);
            *(s8v*)&sFeat[pix * 72 + q * 8] = v;
        }
    }
    __syncthreads();

    // ---- phase 1b: om MFMA (r3-offmod geometry, verified) ----
    {
        f4v acc2[2];
        acc2[0] = (f4v)0.f; acc2[1] = (f4v)0.f;
        const int p = wave * 16 + lm;
        const int prow = p >> 3, pcol = p & 7;
#pragma unroll
        for (int t = 0; t < 9; ++t) {
            const int dy = t / 3, dx = t % 3;
            const int sidx = (prow + dy) * 10 + pcol + dx;
            h8 a[2];
#pragma unroll
            for (int ks = 0; ks < 2; ++ks)
                a[ks] = *(const h8*)&sFeat[sidx * 72 + ks * 32 + kg * 8];
#pragma unroll
            for (int nt = 0; nt < 2; ++nt) {
                const int o = nt * 16 + lm;
#pragma unroll
                for (int ks = 0; ks < 2; ++ks) {
                    const h8 bf = *(const h8*)(Womt + ((size_t)(t * 32 + o)) * 64 +
                                               ks * 32 + kg * 8);
                    acc2[nt] = __builtin_amdgcn_mfma_f32_16x16x32_f16(
                        a[ks], bf, acc2[nt], 0, 0, 0);
                }
            }
        }
#pragma unroll
        for (int nt = 0; nt < 2; ++nt) {
            const int o = nt * 16 + lm;
            if (o < 27) {
#pragma unroll
                for (int r = 0; r < 4; ++r) {
                    const int pp = wave * 16 + kg * 4 + r;
                    if (o < 18) sOm[pp * 28 + o] = acc2[nt][r] + boff[o];
                    else {
                        const float z = acc2[nt][r] + bmod[o - 18];
                        sOm[pp * 28 + o] = 2.f / (1.f + expf(-z));
                    }
                }
            }
        }
    }
    __syncthreads();   // sOm complete; sFeat reads done

    // ---- phase 2: bilinear records (mod folded into corner weights) ----
    for (int idx = tid; idx < 576; idx += 256) {
        const int p = idx & 63, k = idx >> 6;
        const int yy = y0 + (p >> 3), xx = x0 + (p & 7);
        const float dy = sOm[p * 28 + 2 * k];
        const float dx = sOm[p * 28 + 2 * k + 1];
        const float m  = sOm[p * 28 + 18 + k];
        const float pyf = (float)(yy + (k / 3) - 1) + dy;
        const float pxf = (float)(xx + (k % 3) - 1) + dx;
        const float fy0 = floorf(pyf), fx0 = floorf(pxf);
        const float wy1 = pyf - fy0, wx1 = pxf - fx0;
        const int iy0 = (int)fy0, ix0 = (int)fx0;
        const float w[4] = { m * (1.f - wy1) * (1.f - wx1), m * (1.f - wy1) * wx1,
                             m * wy1 * (1.f - wx1),         m * wy1 * wx1 };
        const int ys[4] = { iy0, iy0, iy0 + 1, iy0 + 1 };
        const int xs[4] = { ix0, ix0 + 1, ix0, ix0 + 1 };
#pragma unroll
        for (int cn = 0; cn < 4; ++cn) {
            const bool valid = ((unsigned)ys[cn] < (unsigned)HH) &&
                               ((unsigned)xs[cn] < (unsigned)WW);
            sOffs[idx * 4 + cn] = valid ? (ys[cn] * WW + xs[cn]) * CC : 0;
            sWts[idx * 4 + cn]  = f2h(valid ? w[cn] : 0.f);
        }
    }
    __syncthreads();   // records ready; sFeat fully dead

    // ---- phase 3: r5 gather loop ----
    const int p1 = tid >> 2;
    const int cb = (tid & 3) * 16;

    f4v acc[2][2];
#pragma unroll
    for (int i = 0; i < 2; ++i)
#pragma unroll
        for (int j = 0; j < 2; ++j) acc[i][j] = (f4v)0.f;

    h8 cr[8];
    u4v wt4;

    auto load_gather = [&](int k) {
        const int rec = (k * 64 + p1) * 4;
        const int4 off4 = *(const int4*)&sOffs[rec];
        wt4 = *(const u4v*)&sWts[rec];
        const u16* c0p = fb + off4.x + cb;
        const u16* c1p = fb + off4.y + cb;
        const u16* c2p = fb + off4.z + cb;
        const u16* c3p = fb + off4.w + cb;
        cr[0] = *(const h8*)c0p; cr[1] = *(const h8*)(c0p + 8);
        cr[2] = *(const h8*)c1p; cr[3] = *(const h8*)(c1p + 8);
        cr[4] = *(const h8*)c2p; cr[5] = *(const h8*)(c2p + 8);
        cr[6] = *(const h8*)c3p; cr[7] = *(const h8*)(c3p + 8);
    };

    load_gather(0);

    for (int k = 0; k < 9; ++k) {
        h8 w8 = (h8)h_from_bits(wt4.x);
        h8 a0 = w8 * cr[0];
        h8 a1 = w8 * cr[1];
        w8 = (h8)h_from_bits(wt4.y);
        a0 += w8 * cr[2]; a1 += w8 * cr[3];
        w8 = (h8)h_from_bits(wt4.z);
        a0 += w8 * cr[4]; a1 += w8 * cr[5];
        w8 = (h8)h_from_bits(wt4.w);
        a0 += w8 * cr[6]; a1 += w8 * cr[7];

        u16* vbuf = sV + (k & 1) * 4608;
        *(h8*)&vbuf[p1 * 72 + cb]     = a0;
        *(h8*)&vbuf[p1 * 72 + cb + 8] = a1;

        __syncthreads();

        if (k < 8) load_gather(k + 1);

        h8 a[2][2], bf[2][2];
#pragma unroll
        for (int nt = 0; nt < 2; ++nt) {
            const int oc = wj * 32 + nt * 16 + lm;
#pragma unroll
            for (int ks = 0; ks < 2; ++ks)
                bf[nt][ks] = *(const h8*)(Wdt + ((size_t)(k * 64 + oc)) * 64 +
                                          ks * 32 + kg * 8);
        }
#pragma unroll
        for (int mt = 0; mt < 2; ++mt) {
            const int p = wi * 32 + mt * 16 + lm;
#pragma unroll
            for (int ks = 0; ks < 2; ++ks)
                a[mt][ks] = *(const h8*)&vbuf[p * 72 + ks * 32 + kg * 8];
        }
#pragma unroll
        for (int mt = 0; mt < 2; ++mt)
#pragma unroll
            for (int nt = 0; nt < 2; ++nt)
#pragma unroll
                for (int ks = 0; ks < 2; ++ks)
                    acc[mt][nt] = __builtin_amdgcn_mfma_f32_16x16x32_f16(
                        a[mt][ks], bf[nt][ks], acc[mt][nt], 0, 0, 0);
    }

    // epilogue: NCHW fp32
#pragma unroll
    for (int mt = 0; mt < 2; ++mt)
#pragma unroll
        for (int nt = 0; nt < 2; ++nt) {
            const int oc = wj * 32 + nt * 16 + lm;
            const float bias = bdcn[oc];
#pragma unroll
            for (int r = 0; r < 4; ++r) {
                const int p = wi * 32 + mt * 16 + kg * 4 + r;
                const int y = y0 + (p >> 3), x = x0 + (p & 7);
                out[(((size_t)b * CC + oc) * HH + y) * WW + x] = acc[mt][nt][r] + bias;
            }
        }
}

extern "C" void kernel_launch(void* const* d_in, const int* in_sizes, int n_in,
                              void* d_out, int out_size, void* d_ws, size_t ws_size,
                              hipStream_t stream)
{
    const float* xvq  = (const float*)d_in[0];
    const float* xres = (const float*)d_in[1];
    const float* W1   = (const float*)d_in[2];
    const float* b1   = (const float*)d_in[3];
    const float* Woff = (const float*)d_in[4];
    const float* boff = (const float*)d_in[5];
    const float* Wmod = (const float*)d_in[6];
    const float* bmod = (const float*)d_in[7];
    const float* Wdcn = (const float*)d_in[8];
    const float* bdcn = (const float*)d_in[9];
    float* out = (float*)d_out;

    u16* feath = (u16*)d_ws;                               // 8.39M u16
    u16* W1t   = feath + (size_t)BB * HH * WW * CC;        // 73728 u16
    u16* Womt  = W1t + 9 * 64 * 128;                       // 18432 u16
    u16* Wdt   = Womt + 9 * 32 * 64;                       // 36864 u16

    wfuse_kernel<<<dim3(504), 256, 0, stream>>>(W1, Woff, Wmod, Wdcn, W1t, Womt, Wdt);
    conv1_mfma_kernel<<<dim3(8, 8, 8), 256, 0, stream>>>(xvq, xres, W1t, b1, feath);
    dcn_mfma_kernel<<<dim3(16, 16, 8), 256, 0, stream>>>(feath, Womt, Wdt,
                                                         boff, bmod, bdcn, out);
}